// Round 1
// baseline (847.421 us; speedup 1.0000x reference)
//
#include <hip/hip_runtime.h>
#include <math.h>

#define NS   64
#define NOBS 10000
#define NB   256
#define TMAX 2048

// workspace layout (floats)
#define PIP_OFF 0
#define A_OFF   64
#define LSE_OFF (64 + 4096)
#define ET_OFF  (64 + 4096 + 64)
// total floats: 4224 + 640000 = 644224  (~2.58 MB)

__device__ __forceinline__ float rl_f(float v, int lane) {
  return __uint_as_float(__builtin_amdgcn_readlane(__float_as_uint(v), lane));
}

__device__ __forceinline__ float wsum64(float v) {
  v += __shfl_xor(v, 1);
  v += __shfl_xor(v, 2);
  v += __shfl_xor(v, 4);
  v += __shfl_xor(v, 8);
  v += __shfl_xor(v, 16);
  v += __shfl_xor(v, 32);
  return v;
}

// ---------------- precompute: softmax(pi), column-softmax(A) ----------------
__global__ __launch_bounds__(64) void prep_small(const float* __restrict__ pi,
                                                 const float* __restrict__ A,
                                                 float* __restrict__ ws) {
  const int k = threadIdx.x;  // 0..63
  // pi softmax (wave butterfly)
  float p = pi[k];
  float m = p;
  m = fmaxf(m, __shfl_xor(m, 1));
  m = fmaxf(m, __shfl_xor(m, 2));
  m = fmaxf(m, __shfl_xor(m, 4));
  m = fmaxf(m, __shfl_xor(m, 8));
  m = fmaxf(m, __shfl_xor(m, 16));
  m = fmaxf(m, __shfl_xor(m, 32));
  float ex = expf(p - m);
  float s = wsum64(ex);
  ws[PIP_OFF + k] = ex / s;

  // A column-softmax: lane k owns column k (softmax over i, axis=0)
  float cm = -3.0e38f;
  for (int i = 0; i < NS; ++i) cm = fmaxf(cm, A[i * NS + k]);
  float cs = 0.f;
  for (int i = 0; i < NS; ++i) cs += expf(A[i * NS + k] - cm);
  float inv = 1.0f / cs;
  for (int i = 0; i < NS; ++i)
    ws[A_OFF + i * NS + k] = expf(A[i * NS + k] - cm) * inv;
}

// ---------------- precompute: per-state emission logsumexp ----------------
__global__ __launch_bounds__(256) void emis_lse(const float* __restrict__ E,
                                                float* __restrict__ ws) {
  const int s = blockIdx.x;  // state
  const float* row = E + (size_t)s * NOBS;
  __shared__ float red[4];
  float m = -3.0e38f;
  for (int o = threadIdx.x; o < NOBS; o += 256) m = fmaxf(m, row[o]);
  m = fmaxf(m, __shfl_xor(m, 1));
  m = fmaxf(m, __shfl_xor(m, 2));
  m = fmaxf(m, __shfl_xor(m, 4));
  m = fmaxf(m, __shfl_xor(m, 8));
  m = fmaxf(m, __shfl_xor(m, 16));
  m = fmaxf(m, __shfl_xor(m, 32));
  const int wid = threadIdx.x >> 6;
  if ((threadIdx.x & 63) == 0) red[wid] = m;
  __syncthreads();
  m = fmaxf(fmaxf(red[0], red[1]), fmaxf(red[2], red[3]));
  __syncthreads();
  float sum = 0.f;
  for (int o = threadIdx.x; o < NOBS; o += 256) sum += expf(row[o] - m);
  sum = wsum64(sum);
  if ((threadIdx.x & 63) == 0) red[wid] = sum;
  __syncthreads();
  if (threadIdx.x == 0)
    ws[LSE_OFF + s] = m + logf(red[0] + red[1] + red[2] + red[3]);
}

// ---------------- precompute: EprobT[obs*64 + s] = exp(E[s,obs] - lse[s]) ----
__global__ __launch_bounds__(256) void emis_fill(const float* __restrict__ E,
                                                 float* __restrict__ ws) {
  const int idx = blockIdx.x * 256 + threadIdx.x;  // = obs*64 + s
  if (idx >= NS * NOBS) return;
  const int s = idx & 63;
  const int obs = idx >> 6;
  ws[ET_OFF + idx] = expf(E[(size_t)s * NOBS + obs] - ws[LSE_OFF + s]);
}

// ---------------- forward recursion: 1 batch = 1 block = 1 wave ----------------
// STEP(u, XSRC): one time step; u = compile-time slot 0..7 (static epf index)
#define STEP(u, XSRC) do {                                                     \
    const int t_ = tb + j0 + (u);                                              \
    const float e_ = epf[(u)];                                                 \
    { const int obspf_ = __builtin_amdgcn_readlane((XSRC), (j0 + (u) + 8) & 63);\
      if (t_ + 8 < TMAX) epf[(u)] = ET[obspf_ * NS + lane]; }                  \
    float ac0_ = 0.f, ac1_ = 0.f, ac2_ = 0.f, ac3_ = 0.f;                      \
    _Pragma("unroll")                                                          \
    for (int k_ = 0; k_ < NS; k_ += 4) {                                       \
      ac0_ = fmaf(a[k_ + 0], rl_f(v, k_ + 0), ac0_);                           \
      ac1_ = fmaf(a[k_ + 1], rl_f(v, k_ + 1), ac1_);                           \
      ac2_ = fmaf(a[k_ + 2], rl_f(v, k_ + 2), ac2_);                           \
      ac3_ = fmaf(a[k_ + 3], rl_f(v, k_ + 3), ac3_);                           \
    }                                                                          \
    const float base_ = (t_ == 0) ? pip : ((ac0_ + ac1_) + (ac2_ + ac3_));     \
    float w_ = e_ * base_;                                                     \
    if (t_ == Tn - 1) { vs = w_; e2s = E2; }                                   \
    if (((u) & 1) != 0) {  /* power-of-2 rescale every 2 steps */              \
      const float w0_ = rl_f(w_, 0);                                           \
      int se_ = ilogbf(w0_);                                                   \
      se_ = (se_ < -200 || se_ > 200) ? 0 : se_;                               \
      w_ = ldexpf(w_, -se_);                                                   \
      E2 += se_;                                                               \
    }                                                                          \
    v = w_;                                                                    \
  } while (0)

__global__ __launch_bounds__(64) void hmm_fwd(const int* __restrict__ x,
                                              const int* __restrict__ T,
                                              const float* __restrict__ ws,
                                              float* __restrict__ out) {
  const int lane = threadIdx.x;
  const int b = blockIdx.x;
  const float* __restrict__ Ap = ws + A_OFF;
  const float* __restrict__ ET = ws + ET_OFF;
  const int* __restrict__ xb = x + (size_t)b * TMAX;
  const int Tn = T[b];

  // row i of A_prob into 64 VGPRs (lane i)
  float a[NS];
  {
    const float4* ar = (const float4*)(Ap + lane * NS);
#pragma unroll
    for (int q = 0; q < NS / 4; ++q) {
      float4 f = ar[q];
      a[4 * q + 0] = f.x; a[4 * q + 1] = f.y;
      a[4 * q + 2] = f.z; a[4 * q + 3] = f.w;
    }
  }
  const float pip = ws[PIP_OFF + lane];

  const int nch = (Tn + 63) >> 6;
  int xv = xb[lane];          // x chunk c   (t in [64c, 64c+64))
  int xvn = xb[64 + lane];    // x chunk c+1

  // emission prefetch pipeline, depth 8, statically indexed
  float epf[8];
#pragma unroll
  for (int u = 0; u < 8; ++u) {
    const int obs0 = __builtin_amdgcn_readlane(xv, u);
    epf[u] = ET[obs0 * NS + lane];
  }

  float v = 0.f, vs = 0.f;
  int E2 = 0, e2s = 0;

  for (int c = 0; c < nch; ++c) {
    const int tb = c << 6;
    for (int j0 = 0; j0 < 56; j0 += 8) {  // prefetch source: current chunk
      STEP(0, xv); STEP(1, xv); STEP(2, xv); STEP(3, xv);
      STEP(4, xv); STEP(5, xv); STEP(6, xv); STEP(7, xv);
    }
    {
      const int j0 = 56;                  // prefetch source: next chunk
      STEP(0, xvn); STEP(1, xvn); STEP(2, xvn); STEP(3, xvn);
      STEP(4, xvn); STEP(5, xvn); STEP(6, xvn); STEP(7, xvn);
    }
    xv = xvn;
    xvn = ((c + 2) < (TMAX >> 6)) ? xb[((c + 2) << 6) + lane] : 0;
  }

  const float sf = wsum64(vs);
  if (lane == 0) {
    const double lp = (double)logf(sf) + (double)e2s * 0.6931471805599453;
    out[b] = (float)lp;
  }
}

extern "C" void kernel_launch(void* const* d_in, const int* in_sizes, int n_in,
                              void* d_out, int out_size, void* d_ws, size_t ws_size,
                              hipStream_t stream) {
  const int*   x  = (const int*)d_in[0];
  const int*   T  = (const int*)d_in[1];
  const float* pi = (const float*)d_in[2];
  const float* A  = (const float*)d_in[3];
  const float* E  = (const float*)d_in[4];
  float* out = (float*)d_out;
  float* ws  = (float*)d_ws;

  prep_small<<<1, 64, 0, stream>>>(pi, A, ws);
  emis_lse<<<NS, 256, 0, stream>>>(E, ws);
  emis_fill<<<(NS * NOBS + 255) / 256, 256, 0, stream>>>(E, ws);
  hmm_fwd<<<NB, 64, 0, stream>>>(x, T, ws, out);
}

// Round 2
// 770.702 us; speedup vs baseline: 1.0995x; 1.0995x over previous
//
#include <hip/hip_runtime.h>
#include <math.h>

#define NS   64
#define NOBS 10000
#define NB   256
#define TMAX 2048

// workspace layout (floats)
#define PIP_OFF 0
#define A_OFF   64
#define LSE_OFF (64 + 4096)
#define ET_OFF  (64 + 4096 + 64)
// total floats: 4224 + 640000 = 644224  (~2.58 MB)

__device__ __forceinline__ float wsum64(float v) {
  v += __shfl_xor(v, 1);
  v += __shfl_xor(v, 2);
  v += __shfl_xor(v, 4);
  v += __shfl_xor(v, 8);
  v += __shfl_xor(v, 16);
  v += __shfl_xor(v, 32);
  return v;
}

// ---------------- precompute: softmax(pi), column-softmax(A) ----------------
__global__ __launch_bounds__(64) void prep_small(const float* __restrict__ pi,
                                                 const float* __restrict__ A,
                                                 float* __restrict__ ws) {
  const int k = threadIdx.x;  // 0..63
  float p = pi[k];
  float m = p;
  m = fmaxf(m, __shfl_xor(m, 1));
  m = fmaxf(m, __shfl_xor(m, 2));
  m = fmaxf(m, __shfl_xor(m, 4));
  m = fmaxf(m, __shfl_xor(m, 8));
  m = fmaxf(m, __shfl_xor(m, 16));
  m = fmaxf(m, __shfl_xor(m, 32));
  float ex = expf(p - m);
  float s = wsum64(ex);
  ws[PIP_OFF + k] = ex / s;

  // A column-softmax: lane k owns column k (softmax over i, axis=0)
  float cm = -3.0e38f;
  for (int i = 0; i < NS; ++i) cm = fmaxf(cm, A[i * NS + k]);
  float cs = 0.f;
  for (int i = 0; i < NS; ++i) cs += expf(A[i * NS + k] - cm);
  float inv = 1.0f / cs;
  for (int i = 0; i < NS; ++i)
    ws[A_OFF + i * NS + k] = expf(A[i * NS + k] - cm) * inv;
}

// ---------------- precompute: per-state emission logsumexp ----------------
__global__ __launch_bounds__(256) void emis_lse(const float* __restrict__ E,
                                                float* __restrict__ ws) {
  const int s = blockIdx.x;  // state
  const float* row = E + (size_t)s * NOBS;
  __shared__ float red[4];
  float m = -3.0e38f;
  for (int o = threadIdx.x; o < NOBS; o += 256) m = fmaxf(m, row[o]);
  m = fmaxf(m, __shfl_xor(m, 1));
  m = fmaxf(m, __shfl_xor(m, 2));
  m = fmaxf(m, __shfl_xor(m, 4));
  m = fmaxf(m, __shfl_xor(m, 8));
  m = fmaxf(m, __shfl_xor(m, 16));
  m = fmaxf(m, __shfl_xor(m, 32));
  const int wid = threadIdx.x >> 6;
  if ((threadIdx.x & 63) == 0) red[wid] = m;
  __syncthreads();
  m = fmaxf(fmaxf(red[0], red[1]), fmaxf(red[2], red[3]));
  __syncthreads();
  float sum = 0.f;
  for (int o = threadIdx.x; o < NOBS; o += 256) sum += expf(row[o] - m);
  sum = wsum64(sum);
  if ((threadIdx.x & 63) == 0) red[wid] = sum;
  __syncthreads();
  if (threadIdx.x == 0)
    ws[LSE_OFF + s] = m + logf(red[0] + red[1] + red[2] + red[3]);
}

// ---------------- precompute: EprobT[obs*64 + s] = exp(E[s,obs] - lse[s]) ----
__global__ __launch_bounds__(256) void emis_fill(const float* __restrict__ E,
                                                 float* __restrict__ ws) {
  const int idx = blockIdx.x * 256 + threadIdx.x;  // = obs*64 + s
  if (idx >= NS * NOBS) return;
  const int s = idx & 63;
  const int obs = idx >> 6;
  ws[ET_OFF + idx] = expf(E[(size_t)s * NOBS + obs] - ws[LSE_OFF + s]);
}

// ---------------- forward recursion: 1 batch = 1 block = 1 wave ----------------
// Per step: ds_write alpha (2 lanes/bank, free) -> 16x ds_read_b128 broadcast
// (uniform address, conflict-free) -> 64 v_fmac with VGPR-only operands.
// Rescale every step: se = exponent field of alpha_prev[0] (uniform in all
// lanes, no readlane), folded into the emission value off the critical path.
#define STEP(u, XSRC) do {                                                     \
    const int t_ = tb + j0 + (u);                                              \
    const float e_ = epf[(u)];                                                 \
    { const int obspf_ = __builtin_amdgcn_readlane((XSRC), (j0 + (u) + 8) & 63);\
      if (t_ + 8 < TMAX) epf[(u)] = ET[obspf_ * NS + lane]; }                  \
    float4 q_[16];                                                             \
    _Pragma("unroll")                                                          \
    for (int r_ = 0; r_ < 16; ++r_) q_[r_] = AL[r_];                           \
    float ac0_ = 0.f, ac1_ = 0.f, ac2_ = 0.f, ac3_ = 0.f;                      \
    _Pragma("unroll")                                                          \
    for (int r_ = 0; r_ < 16; ++r_) {                                          \
      ac0_ = fmaf(a[4 * r_ + 0], q_[r_].x, ac0_);                              \
      ac1_ = fmaf(a[4 * r_ + 1], q_[r_].y, ac1_);                              \
      ac2_ = fmaf(a[4 * r_ + 2], q_[r_].z, ac2_);                              \
      ac3_ = fmaf(a[4 * r_ + 3], q_[r_].w, ac3_);                              \
    }                                                                          \
    const int se_ = (int)((__float_as_uint(q_[0].x) >> 23) & 0xFFu) - 127;     \
    const float sc_ = __uint_as_float((unsigned)(127 - se_) << 23);            \
    const float es_ = e_ * sc_;                                                \
    const float base_ = (t_ == 0) ? pip : ((ac0_ + ac1_) + (ac2_ + ac3_));     \
    const float w_ = es_ * base_;                                              \
    E2 += se_;                                                                 \
    if (t_ == Tn - 1) { vs = w_; e2s = E2; }                                   \
    alpha_s[lane] = w_;                                                        \
  } while (0)

__global__ __launch_bounds__(64) void hmm_fwd(const int* __restrict__ x,
                                              const int* __restrict__ T,
                                              const float* __restrict__ ws,
                                              float* __restrict__ out) {
  const int lane = threadIdx.x;
  const int b = blockIdx.x;
  const float* __restrict__ Ap = ws + A_OFF;
  const float* __restrict__ ET = ws + ET_OFF;
  const int* __restrict__ xb = x + (size_t)b * TMAX;
  const int Tn = T[b];

  __shared__ __align__(16) float alpha_s[NS];
  const float4* __restrict__ AL = (const float4*)alpha_s;
  alpha_s[lane] = 1.0f;  // exponent 0 -> se=0 at t=0; single wave, DS in-order

  // row i of A_prob into 64 VGPRs (lane i)
  float a[NS];
  {
    const float4* ar = (const float4*)(Ap + lane * NS);
#pragma unroll
    for (int q = 0; q < NS / 4; ++q) {
      float4 f = ar[q];
      a[4 * q + 0] = f.x; a[4 * q + 1] = f.y;
      a[4 * q + 2] = f.z; a[4 * q + 3] = f.w;
    }
  }
  const float pip = ws[PIP_OFF + lane];

  const int nch = (Tn + 63) >> 6;
  int xv = xb[lane];          // x chunk c   (t in [64c, 64c+64))
  int xvn = xb[64 + lane];    // x chunk c+1

  // emission prefetch pipeline, depth 8, statically indexed
  float epf[8];
#pragma unroll
  for (int u = 0; u < 8; ++u) {
    const int obs0 = __builtin_amdgcn_readlane(xv, u);
    epf[u] = ET[obs0 * NS + lane];
  }

  float vs = 0.f;
  int E2 = 0, e2s = 0;

  for (int c = 0; c < nch; ++c) {
    const int tb = c << 6;
    for (int j0 = 0; j0 < 56; j0 += 8) {  // prefetch source: current chunk
      STEP(0, xv); STEP(1, xv); STEP(2, xv); STEP(3, xv);
      STEP(4, xv); STEP(5, xv); STEP(6, xv); STEP(7, xv);
    }
    {
      const int j0 = 56;                  // prefetch source: next chunk
      STEP(0, xvn); STEP(1, xvn); STEP(2, xvn); STEP(3, xvn);
      STEP(4, xvn); STEP(5, xvn); STEP(6, xvn); STEP(7, xvn);
    }
    xv = xvn;
    xvn = ((c + 2) < (TMAX >> 6)) ? xb[((c + 2) << 6) + lane] : 0;
  }

  const float sf = wsum64(vs);
  if (lane == 0) {
    const double lp = (double)logf(sf) + (double)e2s * 0.6931471805599453;
    out[b] = (float)lp;
  }
}

extern "C" void kernel_launch(void* const* d_in, const int* in_sizes, int n_in,
                              void* d_out, int out_size, void* d_ws, size_t ws_size,
                              hipStream_t stream) {
  const int*   x  = (const int*)d_in[0];
  const int*   T  = (const int*)d_in[1];
  const float* pi = (const float*)d_in[2];
  const float* A  = (const float*)d_in[3];
  const float* E  = (const float*)d_in[4];
  float* out = (float*)d_out;
  float* ws  = (float*)d_ws;

  prep_small<<<1, 64, 0, stream>>>(pi, A, ws);
  emis_lse<<<NS, 256, 0, stream>>>(E, ws);
  emis_fill<<<(NS * NOBS + 255) / 256, 256, 0, stream>>>(E, ws);
  hmm_fwd<<<NB, 64, 0, stream>>>(x, T, ws, out);
}